// Round 7
// baseline (534.223 us; speedup 1.0000x reference)
//
#include <hip/hip_runtime.h>

#define TB 262144

typedef short bf16x8 __attribute__((ext_vector_type(8)));
typedef float f32x16 __attribute__((ext_vector_type(16)));

__device__ __forceinline__ unsigned short f2bf(float f) {
  unsigned int u = __float_as_uint(f);
  unsigned int r = (u + 0x7fffu + ((u >> 16) & 1u)) >> 16;
  return (unsigned short)r;
}
__device__ __forceinline__ float sigmoid_f(float x) {
  return __builtin_amdgcn_rcpf(1.f + __expf(-x));
}
__device__ __forceinline__ float tanh_f(float x) {
  return 1.f - 2.f * __builtin_amdgcn_rcpf(__expf(2.f * x) + 1.f);
}

// Convert the 5 weight matrices to bf16 in workspace.
// Layout (ushort elems): [0,32768) w ; [32768,65536) wi ; [65536,98304) wf ;
//                        [98304,131072) wo ; [131072,147456) w_out
__global__ void wconv_kernel(const float* __restrict__ w, const float* __restrict__ wi,
                             const float* __restrict__ wf, const float* __restrict__ wo,
                             const float* __restrict__ wout, unsigned short* __restrict__ dst) {
  int i = blockIdx.x * 256 + threadIdx.x;
  float v;
  if (i < 32768) v = w[i];
  else if (i < 65536) v = wi[i - 32768];
  else if (i < 98304) v = wf[i - 65536];
  else if (i < 131072) v = wo[i - 98304];
  else v = wout[i - 131072];
  dst[i] = f2bf(v);
}

// 32 rows/block, 4 waves; wave w owns cols [32w,32w+32) via 32x32x16 MFMA.
// NO input staging: A-fragments are loaded straight from global f32 inside
// the K-loop (lane l covers row l&31; lanes l/l+32 complete 64B sectors),
// converted to bf16 inline. HBM loads issue continuously through the whole
// K-loop instead of in a burst -> sustained memory-level parallelism.
// Only LDS use: h exchange for GEMM2 (8 KB), one __syncthreads.
__global__ __launch_bounds__(256, 3) void lstm_main(
    const float* __restrict__ c_prev, const float* __restrict__ h_prev,
    const float* __restrict__ x, const unsigned short* __restrict__ wbf,
    const float* __restrict__ b, const float* __restrict__ bi,
    const float* __restrict__ bf_, const float* __restrict__ bo,
    const float* __restrict__ b_out,
    float* __restrict__ out_c, float* __restrict__ out_h, float* __restrict__ out_y) {
  __shared__ unsigned short us_h[4096];  // 8 KB: h bf16 [32][128], XOR-swizzled

  const int tid = threadIdx.x;
  const int wave = tid >> 6;
  const int lane = tid & 63;
  const int l31 = lane & 31;
  const int lhi = lane >> 5;        // 0/1
  const int row0 = blockIdx.x * 32;
  const int jcol = wave * 32 + l31;

  // Per-lane A-row base (f32): row = row0 + l31, k-half = lhi*8
  const float* xrow = &x[(size_t)(row0 + l31) * 128 + lhi * 8];
  const float* hrow = &h_prev[(size_t)(row0 + l31) * 128 + lhi * 8];

  // c_prev prefetch (full 128B lines); in flight under the K-loop.
  float cpre[16];
#pragma unroll
  for (int reg = 0; reg < 16; ++reg) {
    const int r = (reg & 3) + 8 * (reg >> 2) + 4 * lhi;
    cpre[reg] = c_prev[(size_t)(row0 + r) * 128 + jcol];
  }
  const float bz_s = b[jcol];
  const float bi_s = bi[jcol];
  const float bf_s = bf_[jcol];
  const float bo_s = bo[jcol];

  // ---- GEMM1: K=256 in 16 steps of 32x32x16, 4 gates, A direct from HBM ----
  f32x16 accz = {}, acci = {}, accf = {}, acco = {};
#pragma unroll
  for (int kk = 0; kk < 16; ++kk) {
    const float* asrc = (kk < 8) ? &xrow[kk * 16] : &hrow[(kk - 8) * 16];
    const float4 a0 = *reinterpret_cast<const float4*>(asrc);
    const float4 a1 = *reinterpret_cast<const float4*>(asrc + 4);
    bf16x8 a8;
    a8[0] = (short)f2bf(a0.x); a8[1] = (short)f2bf(a0.y);
    a8[2] = (short)f2bf(a0.z); a8[3] = (short)f2bf(a0.w);
    a8[4] = (short)f2bf(a1.x); a8[5] = (short)f2bf(a1.y);
    a8[6] = (short)f2bf(a1.z); a8[7] = (short)f2bf(a1.w);

    const int kb = kk * 16 + lhi * 8;
    const int woff = jcol * 256 + kb;
    const bf16x8 bz8 = *reinterpret_cast<const bf16x8*>(&wbf[woff]);
    const bf16x8 bi8 = *reinterpret_cast<const bf16x8*>(&wbf[32768 + woff]);
    const bf16x8 bf8 = *reinterpret_cast<const bf16x8*>(&wbf[65536 + woff]);
    const bf16x8 bo8 = *reinterpret_cast<const bf16x8*>(&wbf[98304 + woff]);
    accz = __builtin_amdgcn_mfma_f32_32x32x16_bf16(a8, bz8, accz, 0, 0, 0);
    acci = __builtin_amdgcn_mfma_f32_32x32x16_bf16(a8, bi8, acci, 0, 0, 0);
    accf = __builtin_amdgcn_mfma_f32_32x32x16_bf16(a8, bf8, accf, 0, 0, 0);
    acco = __builtin_amdgcn_mfma_f32_32x32x16_bf16(a8, bo8, acco, 0, 0, 0);
  }

  // ---- Elementwise epilogue: direct full-line c/h stores ----
#pragma unroll
  for (int reg = 0; reg < 16; ++reg) {
    const int r = (reg & 3) + 8 * (reg >> 2) + 4 * lhi;
    const size_t gi = (size_t)(row0 + r) * 128 + jcol;
    const float z  = tanh_f(accz[reg] + bz_s);
    const float zi = sigmoid_f(acci[reg] + bi_s);
    const float zf = sigmoid_f(accf[reg] + bf_s);
    const float zo = sigmoid_f(acco[reg] + bo_s);
    const float cvv = zf * cpre[reg] + zi * z;
    const float hvv = zo * tanh_f(cvv);
    out_c[gi] = cvv;
    out_h[gi] = hvv;
    us_h[(r * 128 + jcol) ^ ((r & 7) << 3)] = f2bf(hvv);
  }
  __syncthreads();

  // ---- GEMM2: y = sigmoid(h @ w_out^T + b_out), K=128 in 8 steps ----
  f32x16 accy = {};
#pragma unroll
  for (int ks = 0; ks < 8; ++ks) {
    const int kb = ks * 16 + lhi * 8;
    const bf16x8 a8 =
        *reinterpret_cast<const bf16x8*>(&us_h[(l31 * 128 + kb) ^ ((l31 & 7) << 3)]);
    const bf16x8 bw =
        *reinterpret_cast<const bf16x8*>(&wbf[131072 + jcol * 128 + kb]);
    accy = __builtin_amdgcn_mfma_f32_32x32x16_bf16(a8, bw, accy, 0, 0, 0);
  }
  const float by_s = b_out[jcol];
#pragma unroll
  for (int reg = 0; reg < 16; ++reg) {
    const int r = (reg & 3) + 8 * (reg >> 2) + 4 * lhi;
    out_y[(size_t)(row0 + r) * 128 + jcol] = sigmoid_f(accy[reg] + by_s);
  }
}

extern "C" void kernel_launch(void* const* d_in, const int* in_sizes, int n_in,
                              void* d_out, int out_size, void* d_ws, size_t ws_size,
                              hipStream_t stream) {
  const float* c_    = (const float*)d_in[0];
  const float* h_    = (const float*)d_in[1];
  const float* x     = (const float*)d_in[2];
  const float* w     = (const float*)d_in[3];
  const float* wi    = (const float*)d_in[4];
  const float* wf    = (const float*)d_in[5];
  const float* wo    = (const float*)d_in[6];
  const float* wout  = (const float*)d_in[7];
  const float* b     = (const float*)d_in[8];
  const float* bi    = (const float*)d_in[9];
  const float* bf_   = (const float*)d_in[10];
  const float* bo    = (const float*)d_in[11];
  const float* b_out = (const float*)d_in[12];

  unsigned short* wbf = (unsigned short*)d_ws;  // 147456 ushorts = 288 KiB
  float* out_c = (float*)d_out;
  float* out_h = out_c + (size_t)TB * 128;
  float* out_y = out_h + (size_t)TB * 128;

  hipLaunchKernelGGL(wconv_kernel, dim3(576), dim3(256), 0, stream,
                     w, wi, wf, wo, wout, wbf);
  hipLaunchKernelGGL(lstm_main, dim3(8192), dim3(256), 0, stream,
                     c_, h_, x, wbf, b, bi, bf_, bo, b_out, out_c, out_h, out_y);
}

// Round 9
// 377.688 us; speedup vs baseline: 1.4145x; 1.4145x over previous
//
#include <hip/hip_runtime.h>

#define TB 262144

typedef short bf16x8 __attribute__((ext_vector_type(8)));
typedef float f32x16 __attribute__((ext_vector_type(16)));
typedef float f32x4v __attribute__((ext_vector_type(4)));

__device__ __forceinline__ unsigned short f2bf(float f) {
  unsigned int u = __float_as_uint(f);
  unsigned int r = (u + 0x7fffu + ((u >> 16) & 1u)) >> 16;
  return (unsigned short)r;
}
__device__ __forceinline__ float sigmoid_f(float x) {
  return __builtin_amdgcn_rcpf(1.f + __expf(-x));
}
__device__ __forceinline__ float tanh_f(float x) {
  return 1.f - 2.f * __builtin_amdgcn_rcpf(__expf(2.f * x) + 1.f);
}

// LDS-only barrier: wait for LDS ops, NOT global stores/loads (the compiler's
// __syncthreads drains vmcnt(0), stalling every wave on HBM store-acks).
#define LDS_BARRIER() asm volatile("s_waitcnt lgkmcnt(0)\n\ts_barrier" ::: "memory")

// Convert the 5 weight matrices to bf16 in workspace.
// Layout (ushort elems): [0,32768) w ; [32768,65536) wi ; [65536,98304) wf ;
//                        [98304,131072) wo ; [131072,147456) w_out
__global__ void wconv_kernel(const float* __restrict__ w, const float* __restrict__ wi,
                             const float* __restrict__ wf, const float* __restrict__ wo,
                             const float* __restrict__ wout, unsigned short* __restrict__ dst) {
  int i = blockIdx.x * 256 + threadIdx.x;
  float v;
  if (i < 32768) v = w[i];
  else if (i < 65536) v = wi[i - 32768];
  else if (i < 98304) v = wf[i - 65536];
  else if (i < 131072) v = wo[i - 98304];
  else v = wout[i - 131072];
  dst[i] = f2bf(v);
}

// 32 rows/block, 4 waves; wave w owns cols [32w,32w+32) via 32x32x16 MFMA.
// Full 128B-line global accesses throughout; zero cross-loop register state.
// LDS-only barriers keep HBM stores/loads in flight across phase boundaries.
__global__ __launch_bounds__(256, 4) void lstm_main(
    const float* __restrict__ c_prev, const float* __restrict__ h_prev,
    const float* __restrict__ x, const unsigned short* __restrict__ wbf,
    const float* __restrict__ b, const float* __restrict__ bi,
    const float* __restrict__ bf_, const float* __restrict__ bo,
    const float* __restrict__ b_out,
    float* __restrict__ out_c, float* __restrict__ out_h, float* __restrict__ out_y) {
  __shared__ unsigned short us_xh[8192];  // 16 KB: xh bf16 [32][256], XOR-swizzled
  __shared__ unsigned short us_h[4096];   //  8 KB: h  bf16 [32][128], XOR-swizzled

  const int tid = threadIdx.x;
  const int wave = tid >> 6;
  const int lane = tid & 63;
  const int l31 = lane & 31;
  const int lhi = lane >> 5;        // 0/1
  const int kb_lane = lhi * 8;      // A/B fragment k-half
  const int row0 = blockIdx.x * 32;
  const int jcol = wave * 32 + l31;

  // ---- Phase A: stage xh -> LDS (bf16, XOR-swizzled), fully coalesced ----
  {
#pragma unroll
    for (int it = 0; it < 4; ++it) {
      const int cid = it * 256 + tid;      // 0..1023
      const int r = cid >> 5;              // 0..31
      const int c4 = (cid & 31) * 4;       // 0..124
      const f32x4v vx = __builtin_nontemporal_load(
          reinterpret_cast<const f32x4v*>(&x[(size_t)(row0 + r) * 128 + c4]));
      ushort4 ux; ux.x = f2bf(vx.x); ux.y = f2bf(vx.y); ux.z = f2bf(vx.z); ux.w = f2bf(vx.w);
      *reinterpret_cast<ushort4*>(&us_xh[(r * 256 + c4) ^ ((r & 7) << 3)]) = ux;
    }
#pragma unroll
    for (int it = 0; it < 4; ++it) {
      const int cid = it * 256 + tid;
      const int r = cid >> 5;
      const int c4 = (cid & 31) * 4;
      const f32x4v vh = __builtin_nontemporal_load(
          reinterpret_cast<const f32x4v*>(&h_prev[(size_t)(row0 + r) * 128 + c4]));
      ushort4 uh; uh.x = f2bf(vh.x); uh.y = f2bf(vh.y); uh.z = f2bf(vh.z); uh.w = f2bf(vh.w);
      *reinterpret_cast<ushort4*>(&us_xh[(r * 256 + 128 + c4) ^ ((r & 7) << 3)]) = uh;
    }
  }
  LDS_BARRIER();

  // ---- c_prev prefetch: full-line coalesced; latency hides under K-loop ----
  float cpre[16];
#pragma unroll
  for (int reg = 0; reg < 16; ++reg) {
    const int r = (reg & 3) + 8 * (reg >> 2) + 4 * lhi;
    cpre[reg] = __builtin_nontemporal_load(&c_prev[(size_t)(row0 + r) * 128 + jcol]);
  }
  const float bz_s = b[jcol];
  const float bi_s = bi[jcol];
  const float bf_s = bf_[jcol];
  const float bo_s = bo[jcol];

  // ---- Phase B: GEMM1, K=256 in 16 steps of 32x32x16, 4 gates ----
  f32x16 accz = {}, acci = {}, accf = {}, acco = {};
#pragma unroll
  for (int kk = 0; kk < 16; ++kk) {
    const int kb = kk * 16 + kb_lane;
    const bf16x8 a8 =
        *reinterpret_cast<const bf16x8*>(&us_xh[(l31 * 256 + kb) ^ ((l31 & 7) << 3)]);
    const int woff = jcol * 256 + kb;
    const bf16x8 bz8 = *reinterpret_cast<const bf16x8*>(&wbf[woff]);
    const bf16x8 bi8 = *reinterpret_cast<const bf16x8*>(&wbf[32768 + woff]);
    const bf16x8 bf8 = *reinterpret_cast<const bf16x8*>(&wbf[65536 + woff]);
    const bf16x8 bo8 = *reinterpret_cast<const bf16x8*>(&wbf[98304 + woff]);
    accz = __builtin_amdgcn_mfma_f32_32x32x16_bf16(a8, bz8, accz, 0, 0, 0);
    acci = __builtin_amdgcn_mfma_f32_32x32x16_bf16(a8, bi8, acci, 0, 0, 0);
    accf = __builtin_amdgcn_mfma_f32_32x32x16_bf16(a8, bf8, accf, 0, 0, 0);
    acco = __builtin_amdgcn_mfma_f32_32x32x16_bf16(a8, bo8, acco, 0, 0, 0);
  }

  // ---- Phase C: elementwise epilogue, direct full-line nt stores ----
#pragma unroll
  for (int reg = 0; reg < 16; ++reg) {
    const int r = (reg & 3) + 8 * (reg >> 2) + 4 * lhi;
    const size_t gi = (size_t)(row0 + r) * 128 + jcol;
    const float z  = tanh_f(accz[reg] + bz_s);
    const float zi = sigmoid_f(acci[reg] + bi_s);
    const float zf = sigmoid_f(accf[reg] + bf_s);
    const float zo = sigmoid_f(acco[reg] + bo_s);
    const float cvv = zf * cpre[reg] + zi * z;
    const float hvv = zo * tanh_f(cvv);
    __builtin_nontemporal_store(cvv, &out_c[gi]);
    __builtin_nontemporal_store(hvv, &out_h[gi]);
    us_h[(r * 128 + jcol) ^ ((r & 7) << 3)] = f2bf(hvv);
  }
  LDS_BARRIER();  // only LDS (us_h) must be visible; c/h stores stay in flight

  // ---- Phase D: GEMM2 (y = sigmoid(h @ w_out^T + b_out)), K=128 in 8 steps ----
  f32x16 accy = {};
#pragma unroll
  for (int ks = 0; ks < 8; ++ks) {
    const int kb = ks * 16 + kb_lane;
    const bf16x8 a8 =
        *reinterpret_cast<const bf16x8*>(&us_h[(l31 * 128 + kb) ^ ((l31 & 7) << 3)]);
    const bf16x8 bw =
        *reinterpret_cast<const bf16x8*>(&wbf[131072 + jcol * 128 + kb]);
    accy = __builtin_amdgcn_mfma_f32_32x32x16_bf16(a8, bw, accy, 0, 0, 0);
  }
  const float by_s = b_out[jcol];
#pragma unroll
  for (int reg = 0; reg < 16; ++reg) {
    const int r = (reg & 3) + 8 * (reg >> 2) + 4 * lhi;
    __builtin_nontemporal_store(sigmoid_f(accy[reg] + by_s),
                                &out_y[(size_t)(row0 + r) * 128 + jcol]);
  }
}

extern "C" void kernel_launch(void* const* d_in, const int* in_sizes, int n_in,
                              void* d_out, int out_size, void* d_ws, size_t ws_size,
                              hipStream_t stream) {
  const float* c_    = (const float*)d_in[0];
  const float* h_    = (const float*)d_in[1];
  const float* x     = (const float*)d_in[2];
  const float* w     = (const float*)d_in[3];
  const float* wi    = (const float*)d_in[4];
  const float* wf    = (const float*)d_in[5];
  const float* wo    = (const float*)d_in[6];
  const float* wout  = (const float*)d_in[7];
  const float* b     = (const float*)d_in[8];
  const float* bi    = (const float*)d_in[9];
  const float* bf_   = (const float*)d_in[10];
  const float* bo    = (const float*)d_in[11];
  const float* b_out = (const float*)d_in[12];

  unsigned short* wbf = (unsigned short*)d_ws;  // 147456 ushorts = 288 KiB
  float* out_c = (float*)d_out;
  float* out_h = out_c + (size_t)TB * 128;
  float* out_y = out_h + (size_t)TB * 128;

  hipLaunchKernelGGL(wconv_kernel, dim3(576), dim3(256), 0, stream,
                     w, wi, wf, wo, wout, wbf);
  hipLaunchKernelGGL(lstm_main, dim3(8192), dim3(256), 0, stream,
                     c_, h_, x, wbf, b, bi, bf_, bo, b_out, out_c, out_h, out_y);
}